// Round 10
// baseline (231.312 us; speedup 1.0000x reference)
//
#include <hip/hip_runtime.h>
#include <cstdint>
#include <cstddef>

typedef __attribute__((ext_vector_type(8))) _Float16 f16x8;
typedef __attribute__((ext_vector_type(2))) __fp16 h2;
typedef __attribute__((ext_vector_type(16))) float f32x16;

#define LO_SCALE 2048.0f
#define LO_INV   (1.0f / 2048.0f)
// OMEGA/(2*pi): folded into all effective weights/biases so the activation is
// sin(2*pi*acc) = v_fract + v_sin (2 exact HW ops). Wf/bf are NOT scaled.
#define OMEGA_SC 4.774648292756860f

union H8 { f16x8 v; _Float16 h[8]; };
union HU { f16x8 v; h2 p[4]; };

// k-permutation (applied to A-blob, xs stores, Wf load; exact under shared
// perm): storage p (within 32-block: p32 = hq*16 + r) holds original index
// sigma = (r&3) + 8*(r>>2) + 4*hq. Lets the epilogue store C-fragment regs
// 0..15 as 16 CONTIGUOUS halves (2x b128, conflict-free quarter-waves).

// ---------------------------------------------------------------------------
// Fused kernel A+C.
// Blocks [0,768): ka_weff_blob — (OMEGA_SC*Weff) + direct A-fragment blob.
// Blocks [768,1024): kc_small — layer-0 blob + effective biases (both scaled).
// whblob per (tl): [nf(8)][ks(16)][part(2)][lane(64)*8 halves]
// w0blob per t: [nf(8)][part(2)][512 halves]
// beff: [t][k(4)][256] fp32 (scaled), k=0: b0+hb0, k>=1: bh[k-1]+hb[k]
// ---------------------------------------------------------------------------
__global__ __launch_bounds__(256) void kab(
    const float* __restrict__ latents, const float* __restrict__ W0,
    const float* __restrict__ b0, const float* __restrict__ bh,
    const float* __restrict__ HW0, const float* __restrict__ HB,
    const float* __restrict__ Wh, const float* __restrict__ HWh,
    _Float16* __restrict__ w0blob, float* __restrict__ beff,
    _Float16* __restrict__ whblob) {
  __shared__ float lat_t[8192];  // [k][f] : 256 x 32
  int tid = threadIdx.x, bid = blockIdx.x;

  if (bid >= 768) {
    // ---------------- kc_small ----------------
    int id = (bid - 768) * 256 + tid;
    if (id < 32768) {
      int t = id >> 10, rem = id & 1023;
      int r2 = rem & 127, part = r2 >> 6, lane = r2 & 63;
      int nf = rem >> 7;
      int o = nf * 32 + (lane & 31), kc = lane >> 5;
      const float* lat = latents + t * 256;
      H8 outv;
#pragma unroll
      for (int j = 0; j < 8; ++j) outv.h[j] = (_Float16)0.0f;
#pragma unroll
      for (int j = 0; j < 8; ++j) {
        int i = (j & 3) + 8 * (j >> 2) + 16 * kc;  // permuted position -> orig i
        if (i < 3) {
          const float* row = HW0 + (o * 3 + i) * 256;
          float s = W0[o * 3 + i];
          for (int k = 0; k < 256; k += 4)
            s += row[k] * lat[k] + row[k + 1] * lat[k + 1] +
                 row[k + 2] * lat[k + 2] + row[k + 3] * lat[k + 3];
          s *= OMEGA_SC;
          _Float16 hi = (_Float16)s;
          outv.h[j] = part ? (_Float16)((s - (float)hi) * LO_SCALE) : hi;
        }
      }
      *(f16x8*)(w0blob + (size_t)id * 8) = outv.v;
    } else {
      int v = id - 32768;
      int t = v >> 10, k = (v >> 8) & 3, hm = v & 255;
      float base = (k == 0) ? b0[hm] : bh[(k - 1) * 256 + hm];
      const float* lat = latents + t * 256;
      const float* row = HB + (size_t)(k * 256 + hm) * 256;
      float s = base;
      for (int kk = 0; kk < 256; kk += 4)
        s += row[kk] * lat[kk] + row[kk + 1] * lat[kk + 1] +
             row[kk + 2] * lat[kk + 2] + row[kk + 3] * lat[kk + 3];
      beff[v] = s * OMEGA_SC;
    }
    return;
  }

  // ---------------- ka_weff_blob ----------------
  int h = bid & 1, ks = (bid >> 1) & 15, nf = (bid >> 5) & 7, l = bid >> 8;

  {
    int f = tid >> 3, kb = (tid & 7) * 32;
#pragma unroll
    for (int m = 0; m < 32; m += 4) {
      float4 v = *(const float4*)(latents + f * 256 + kb + m);
      lat_t[(kb + m + 0) * 32 + f] = v.x;
      lat_t[(kb + m + 1) * 32 + f] = v.y;
      lat_t[(kb + m + 2) * 32 + f] = v.z;
      lat_t[(kb + m + 3) * 32 + f] = v.w;
    }
  }
  __syncthreads();

  int oo = tid >> 3, jj = tid & 7;
  int o = nf * 32 + oo;
  // permuted fragment position -> original column index i
  int i = (ks >> 1) * 32 + (ks & 1) * 4 + (jj & 3) + 8 * ((jj >> 2) & 1) + 16 * h;
  int r = o * 256 + i;
  const float* rowp = HWh + ((size_t)l * 65536 + (size_t)r) * 256;

  float acc[32];
#pragma unroll
  for (int f = 0; f < 32; ++f) acc[f] = 0.f;

  float curf[16], nxtf[16];
#pragma unroll
  for (int q = 0; q < 4; ++q)
    *(float4*)(curf + q * 4) = *(const float4*)(rowp + q * 4);

  for (int kc = 0; kc < 16; ++kc) {
    if (kc < 15) {
#pragma unroll
      for (int q = 0; q < 4; ++q)
        *(float4*)(nxtf + q * 4) = *(const float4*)(rowp + (kc + 1) * 16 + q * 4);
    }
    const float* lp = lat_t + kc * 512;
#pragma unroll
    for (int m = 0; m < 16; ++m) {
      float hw = curf[m];
#pragma unroll
      for (int fq = 0; fq < 8; ++fq) {
        float4 lv = *(const float4*)(lp + m * 32 + fq * 4);
        acc[fq * 4 + 0] += hw * lv.x;
        acc[fq * 4 + 1] += hw * lv.y;
        acc[fq * 4 + 2] += hw * lv.z;
        acc[fq * 4 + 3] += hw * lv.w;
      }
    }
#pragma unroll
    for (int q = 0; q < 16; ++q) curf[q] = nxtf[q];
  }

  float whv = Wh[l * 65536 + r];
  size_t cbase = (size_t)(nf * 16 + ks) * 1024 + (size_t)h * 256 + (size_t)tid;
#pragma unroll
  for (int t = 0; t < 32; ++t) {
    float w = (acc[t] + whv) * OMEGA_SC;
    _Float16 hi = (_Float16)w;
    _Float16 lo = (_Float16)((w - (float)hi) * LO_SCALE);
    size_t b = (size_t)(t * 3 + l) * 131072 + cbase;
    whblob[b] = hi;
    whblob[b + 512] = lo;
  }
}

// ---------------------------------------------------------------------------
// Kernel B: fused SIREN. Block = one frame x 64 pixels, 4 waves (256 thr).
// Wave wv owns fa=2 o-fragments (o in wv*64..+64) x fb=2 px-fragments.
// Transposed GEMM D[o][px] = sum_k Weff[o][k]*x[px][k], mfma_f32_32x32x16_f16
// split-fp16 (hh->accA; hl+lh (lo pre-scaled 2048)->accB; out=accA+accB/2048).
// R10: (1) k-perm epilogue -> 2x b128 contiguous stores, zero bank conflicts
// (R9 had 4.19M 4-way conflicts from b64 stores); (2) B prefetched one ks
// ahead into registers (hides ~150cy ds_read latency); (3) setprio around
// the 12-MFMA cluster.
// ---------------------------------------------------------------------------
__global__ __launch_bounds__(256, 2) void kb_siren(
    const float* __restrict__ coords, const _Float16* __restrict__ whblob,
    const _Float16* __restrict__ w0blob, const float* __restrict__ beff,
    const float* __restrict__ Wf, const float* __restrict__ bf,
    float* __restrict__ out) {
  __shared__ _Float16 xs_hi[64 * 264];
  __shared__ _Float16 xs_lo[64 * 264];
  __shared__ float wf_s[768];
  __shared__ float red[768];  // [kq(4)][px(64)][3]
  int tid = threadIdx.x;
  int bid0 = blockIdx.x;
  int bid = (bid0 & 7) * 256 + (bid0 >> 3);  // XCD swizzle: 4 frames per XCD
  int t = bid >> 6, tile = bid & 63;
  int wv = tid >> 6, lane = tid & 63, col = lane & 31, h = lane >> 5;

  if (tid < 192) {
    // load Wf permuted: wf_s[c*256 + p] = Wf[c*256 + sigma(p)]
    int c = tid >> 6;
    int pq = (tid & 63) * 4;
    int blk = pq >> 5, p32 = pq & 31, hq = p32 >> 4, rr = p32 & 15;
    int src = c * 256 + blk * 32 + 8 * (rr >> 2) + 4 * hq;
    *(float4*)(wf_s + tid * 4) = *(const float4*)(Wf + src);
  }
  if (tid < 64) {
    const float* cp = coords + (size_t)(t * 4096 + tile * 64 + tid) * 3;
    float c0 = cp[0], c1 = cp[1], c2 = cp[2];
    H8 hv, lv, z;
#pragma unroll
    for (int j = 0; j < 8; ++j) { hv.h[j] = (_Float16)0.f; lv.h[j] = (_Float16)0.f; z.h[j] = (_Float16)0.f; }
    _Float16 h0 = (_Float16)c0, h1 = (_Float16)c1, h2_ = (_Float16)c2;
    hv.h[0] = h0; hv.h[1] = h1; hv.h[2] = h2_;   // sigma(p)=p for p<4
    lv.h[0] = (_Float16)((c0 - (float)h0) * LO_SCALE);
    lv.h[1] = (_Float16)((c1 - (float)h1) * LO_SCALE);
    lv.h[2] = (_Float16)((c2 - (float)h2_) * LO_SCALE);
    *(f16x8*)(xs_hi + tid * 264) = hv.v;
    *(f16x8*)(xs_lo + tid * 264) = lv.v;
    *(f16x8*)(xs_hi + tid * 264 + 8) = z.v;
    *(f16x8*)(xs_lo + tid * 264 + 8) = z.v;
  }
  __syncthreads();

  f32x16 accA[2][2], accB[2][2];  // [fr][pf]

  auto init_bias = [&](int bk) {
#pragma unroll
    for (int fr = 0; fr < 2; ++fr) {
      const float* bp = beff + ((t * 4 + bk) << 8) + (wv * 2 + fr) * 32 + h * 4;
#pragma unroll
      for (int rq = 0; rq < 4; ++rq) {
        float4 bvv = *(const float4*)(bp + rq * 8);
        float ba[4];
        *(float4*)ba = bvv;
#pragma unroll
        for (int q = 0; q < 4; ++q) {
          accA[fr][0][rq * 4 + q] = ba[q];
          accA[fr][1][rq * 4 + q] = ba[q];
          accB[fr][0][rq * 4 + q] = 0.f;
          accB[fr][1][rq * 4 + q] = 0.f;
        }
      }
    }
  };

  // load the wave's 2 A-fragment pairs (hi+lo) for one ks into named regs
  auto aload4 = [&](const _Float16* blobL, int NS, int ks,
                    f16x8& a0h, f16x8& a0l, f16x8& a1h, f16x8& a1l) {
    const _Float16* p0 = blobL + (size_t)(((wv * 2 + 0) * NS + ks) * 2) * 512 + lane * 8;
    const _Float16* p1 = blobL + (size_t)(((wv * 2 + 1) * NS + ks) * 2) * 512 + lane * 8;
    a0h = *(const f16x8*)p0;
    a0l = *(const f16x8*)(p0 + 512);
    a1h = *(const f16x8*)p1;
    a1l = *(const f16x8*)(p1 + 512);
  };

  // load B (hi/lo for both pf) for one ks into named regs
  auto bload = [&](int ks, f16x8& b0h, f16x8& b0l, f16x8& b1h, f16x8& b1l) {
    int off0 = col * 264 + ks * 16 + h * 8;
    int off1 = (32 + col) * 264 + ks * 16 + h * 8;
    b0h = *(const f16x8*)(xs_hi + off0);
    b0l = *(const f16x8*)(xs_lo + off0);
    b1h = *(const f16x8*)(xs_hi + off1);
    b1l = *(const f16x8*)(xs_lo + off1);
  };

  // one ks-step: 12 MFMAs from registers (A reused across pf, B across fr)
  auto mfma12 = [&](f16x8 a0h, f16x8 a0l, f16x8 a1h, f16x8 a1l,
                    f16x8 b0h, f16x8 b0l, f16x8 b1h, f16x8 b1l) {
    __builtin_amdgcn_s_setprio(1);
    accA[0][0] = __builtin_amdgcn_mfma_f32_32x32x16_f16(a0h, b0h, accA[0][0], 0, 0, 0);
    accA[1][0] = __builtin_amdgcn_mfma_f32_32x32x16_f16(a1h, b0h, accA[1][0], 0, 0, 0);
    accA[0][1] = __builtin_amdgcn_mfma_f32_32x32x16_f16(a0h, b1h, accA[0][1], 0, 0, 0);
    accA[1][1] = __builtin_amdgcn_mfma_f32_32x32x16_f16(a1h, b1h, accA[1][1], 0, 0, 0);
    accB[0][0] = __builtin_amdgcn_mfma_f32_32x32x16_f16(a0h, b0l, accB[0][0], 0, 0, 0);
    accB[1][0] = __builtin_amdgcn_mfma_f32_32x32x16_f16(a1h, b0l, accB[1][0], 0, 0, 0);
    accB[0][1] = __builtin_amdgcn_mfma_f32_32x32x16_f16(a0h, b1l, accB[0][1], 0, 0, 0);
    accB[1][1] = __builtin_amdgcn_mfma_f32_32x32x16_f16(a1h, b1l, accB[1][1], 0, 0, 0);
    accB[0][0] = __builtin_amdgcn_mfma_f32_32x32x16_f16(a0l, b0h, accB[0][0], 0, 0, 0);
    accB[1][0] = __builtin_amdgcn_mfma_f32_32x32x16_f16(a1l, b0h, accB[1][0], 0, 0, 0);
    accB[0][1] = __builtin_amdgcn_mfma_f32_32x32x16_f16(a0l, b1h, accB[0][1], 0, 0, 0);
    accB[1][1] = __builtin_amdgcn_mfma_f32_32x32x16_f16(a1l, b1h, accB[1][1], 0, 0, 0);
    __builtin_amdgcn_s_setprio(0);
  };

  // sin(2*pi*x) via exact HW ops (weights pre-scaled by OMEGA/(2*pi))
  auto sin2pi = [](float x) {
    float f, r;
    asm("v_fract_f32 %0, %1" : "=v"(f) : "v"(x));
    asm("v_sin_f32 %0, %1" : "=v"(r) : "v"(f));
    return r;
  };

  // activation + packed RTZ split + k-perm CONTIGUOUS stores: C-frag regs
  // 0..15 land at storage positions h*16 + 0..15 -> 2x b128 per array.
  auto epilogue = [&]() {
#pragma unroll
    for (int fr = 0; fr < 2; ++fr)
#pragma unroll
      for (int pf = 0; pf < 2; ++pf)
#pragma unroll
        for (int r = 0; r < 16; ++r)
          accA[fr][pf][r] = sin2pi(fmaf(accB[fr][pf][r], LO_INV, accA[fr][pf][r]));
    __syncthreads();  // all waves done reading xs for this layer
#pragma unroll
    for (int fr = 0; fr < 2; ++fr)
#pragma unroll
      for (int pf = 0; pf < 2; ++pf) {
        HU h0, h1, l0, l1;
#pragma unroll
        for (int q = 0; q < 4; ++q) {
          float va = accA[fr][pf][2 * q], vb = accA[fr][pf][2 * q + 1];
          h2 hp = __builtin_amdgcn_cvt_pkrtz(va, vb);
          h0.p[q] = hp;
          l0.p[q] = __builtin_amdgcn_cvt_pkrtz((va - (float)hp[0]) * LO_SCALE,
                                               (vb - (float)hp[1]) * LO_SCALE);
          float vc = accA[fr][pf][8 + 2 * q], vd = accA[fr][pf][8 + 2 * q + 1];
          h2 hq_ = __builtin_amdgcn_cvt_pkrtz(vc, vd);
          h1.p[q] = hq_;
          l1.p[q] = __builtin_amdgcn_cvt_pkrtz((vc - (float)hq_[0]) * LO_SCALE,
                                               (vd - (float)hq_[1]) * LO_SCALE);
        }
        int off = (pf * 32 + col) * 264 + wv * 64 + fr * 32 + h * 16;
        *(f16x8*)(xs_hi + off) = h0.v;
        *(f16x8*)(xs_hi + off + 8) = h1.v;
        *(f16x8*)(xs_lo + off) = l0.v;
        *(f16x8*)(xs_lo + off + 8) = l1.v;
      }
    __syncthreads();
  };

  const _Float16* bl0 = whblob + (size_t)(t * 3) * 131072;
  f16x8 c0h, c0l, c1h, c1l, n0h, n0l, n1h, n1l;
  f16x8 cb0h, cb0l, cb1h, cb1l, nb0h, nb0l, nb1h, nb1l;

  // ---- layer 0 (K=16 zero-padded; coords staged in xs[.., 0..15])
  init_bias(0);
  aload4(w0blob + (size_t)t * 8192, 1, 0, c0h, c0l, c1h, c1l);
  bload(0, cb0h, cb0l, cb1h, cb1l);
  mfma12(c0h, c0l, c1h, c1l, cb0h, cb0l, cb1h, cb1l);
  aload4(bl0, 16, 0, c0h, c0l, c1h, c1l);  // prefetch hidden L0 ks0 under epilogue
  epilogue();

  // ---- hidden layers (A ping-pong prefetch + B one-ks-ahead register prefetch)
#pragma unroll
  for (int li = 0; li < 3; ++li) {
    init_bias(li + 1);
    const _Float16* bl = whblob + (size_t)(t * 3 + li) * 131072;
    const _Float16* bln = whblob + (size_t)(t * 3 + li + 1) * 131072;
    bload(0, cb0h, cb0l, cb1h, cb1l);
#pragma unroll
    for (int ks2 = 0; ks2 < 8; ++ks2) {
      int ksB = ks2 * 2 + 1;
      bload(ksB, nb0h, nb0l, nb1h, nb1l);
      aload4(bl, 16, ksB, n0h, n0l, n1h, n1l);
      mfma12(c0h, c0l, c1h, c1l, cb0h, cb0l, cb1h, cb1l);
      if (ksB < 15) {
        bload(ksB + 1, cb0h, cb0l, cb1h, cb1l);
        aload4(bl, 16, ksB + 1, c0h, c0l, c1h, c1l);
      } else if (li < 2) {
        aload4(bln, 16, 0, c0h, c0l, c1h, c1l);  // next layer ks0 under epilogue
      }
      mfma12(n0h, n0l, n1h, n1l, nb0h, nb0l, nb1h, nb1l);
    }
    epilogue();
  }

  // ---- final linear (3 outputs), VALU from LDS; 4 k-groups of 64
  {
    float pc0 = 0.f, pc1 = 0.f, pc2 = 0.f;
    int px = tid & 63, kq = tid >> 6;
#pragma unroll
    for (int cc = 0; cc < 8; ++cc) {
      int k0 = kq * 64 + cc * 8;
      H8 hv, lv;
      hv.v = *(const f16x8*)(xs_hi + px * 264 + k0);
      lv.v = *(const f16x8*)(xs_lo + px * 264 + k0);
#pragma unroll
      for (int j = 0; j < 8; ++j) {
        float xv = (float)hv.h[j] + (float)lv.h[j] * LO_INV;
        pc0 += xv * wf_s[k0 + j];
        pc1 += xv * wf_s[256 + k0 + j];
        pc2 += xv * wf_s[512 + k0 + j];
      }
    }
    red[kq * 192 + px * 3 + 0] = pc0;
    red[kq * 192 + px * 3 + 1] = pc1;
    red[kq * 192 + px * 3 + 2] = pc2;
    __syncthreads();
    if (tid < 192) {
      int p2 = tid / 3, c = tid - p2 * 3;
      float s = bf[c];
#pragma unroll
      for (int q = 0; q < 4; ++q) s += red[q * 192 + p2 * 3 + c];
      out[(size_t)(t * 4096 + tile * 64 + p2) * 3 + c] = s;
    }
  }
}

// ---------------------------------------------------------------------------
extern "C" void kernel_launch(void* const* d_in, const int* in_sizes, int n_in,
                              void* d_out, int out_size, void* d_ws, size_t ws_size,
                              hipStream_t stream) {
  const float* coords  = (const float*)d_in[0];
  const float* latents = (const float*)d_in[1];
  const float* W0      = (const float*)d_in[2];
  const float* b0      = (const float*)d_in[3];
  const float* Wh      = (const float*)d_in[4];
  const float* bh      = (const float*)d_in[5];
  const float* Wf      = (const float*)d_in[6];
  const float* bf      = (const float*)d_in[7];
  const float* HW0     = (const float*)d_in[8];
  const float* HWh     = (const float*)d_in[9];
  const float* HB      = (const float*)d_in[10];
  float* outp = (float*)d_out;

  char* w = (char*)d_ws;
  _Float16* whblob = (_Float16*)w;                   // 12,582,912 halves
  _Float16* w0blob = (_Float16*)(w + 25165824);      // 262,144 halves
  float*    beff   = (float*)(w + 25690112);         // 32,768 floats

  kab<<<1024, 256, 0, stream>>>(latents, W0, b0, bh, HW0, HB, Wh, HWh,
                                w0blob, beff, whblob);
  kb_siren<<<2048, 256, 0, stream>>>(coords, whblob, w0blob, beff, Wf, bf, outp);
}

// Round 11
// 222.706 us; speedup vs baseline: 1.0386x; 1.0386x over previous
//
#include <hip/hip_runtime.h>
#include <cstdint>
#include <cstddef>

typedef __attribute__((ext_vector_type(8))) _Float16 f16x8;
typedef __attribute__((ext_vector_type(2))) __fp16 h2;
typedef __attribute__((ext_vector_type(16))) float f32x16;

#define LO_SCALE 2048.0f
#define LO_INV   (1.0f / 2048.0f)
// OMEGA/(2*pi): folded into all effective weights/biases so the activation is
// sin(2*pi*acc) = v_fract + v_sin (2 exact HW ops). Wf/bf are NOT scaled.
#define OMEGA_SC 4.774648292756860f

union H8 { f16x8 v; _Float16 h[8]; };
union HU { f16x8 v; h2 p[4]; };

// k-permutation (applied to A-blob, xs stores, Wf load; exact under shared
// perm): storage p (within 32-block: p32 = hq*16 + r) holds original index
// sigma = (r&3) + 8*(r>>2) + 4*hq. Lets the epilogue store C-fragment regs
// 0..15 as 16 CONTIGUOUS halves (2x b128, conflict-free quarter-waves).

// ---------------------------------------------------------------------------
// Fused kernel A+C (unchanged from R10, verified absmax 1.22e-3).
// Blocks [0,768): ka_weff_blob — (OMEGA_SC*Weff) + direct A-fragment blob.
// Blocks [768,1024): kc_small — layer-0 blob + effective biases (both scaled).
// whblob per (tl): [nf(8)][ks(16)][part(2)][lane(64)*8 halves]
// w0blob per t: [nf(8)][part(2)][512 halves]
// beff: [t][k(4)][256] fp32 (scaled), k=0: b0+hb0, k>=1: bh[k-1]+hb[k]
// ---------------------------------------------------------------------------
__global__ __launch_bounds__(256) void kab(
    const float* __restrict__ latents, const float* __restrict__ W0,
    const float* __restrict__ b0, const float* __restrict__ bh,
    const float* __restrict__ HW0, const float* __restrict__ HB,
    const float* __restrict__ Wh, const float* __restrict__ HWh,
    _Float16* __restrict__ w0blob, float* __restrict__ beff,
    _Float16* __restrict__ whblob) {
  __shared__ float lat_t[8192];  // [k][f] : 256 x 32
  int tid = threadIdx.x, bid = blockIdx.x;

  if (bid >= 768) {
    // ---------------- kc_small ----------------
    int id = (bid - 768) * 256 + tid;
    if (id < 32768) {
      int t = id >> 10, rem = id & 1023;
      int r2 = rem & 127, part = r2 >> 6, lane = r2 & 63;
      int nf = rem >> 7;
      int o = nf * 32 + (lane & 31), kc = lane >> 5;
      const float* lat = latents + t * 256;
      H8 outv;
#pragma unroll
      for (int j = 0; j < 8; ++j) outv.h[j] = (_Float16)0.0f;
#pragma unroll
      for (int j = 0; j < 8; ++j) {
        int i = (j & 3) + 8 * (j >> 2) + 16 * kc;  // permuted position -> orig i
        if (i < 3) {
          const float* row = HW0 + (o * 3 + i) * 256;
          float s = W0[o * 3 + i];
          for (int k = 0; k < 256; k += 4)
            s += row[k] * lat[k] + row[k + 1] * lat[k + 1] +
                 row[k + 2] * lat[k + 2] + row[k + 3] * lat[k + 3];
          s *= OMEGA_SC;
          _Float16 hi = (_Float16)s;
          outv.h[j] = part ? (_Float16)((s - (float)hi) * LO_SCALE) : hi;
        }
      }
      *(f16x8*)(w0blob + (size_t)id * 8) = outv.v;
    } else {
      int v = id - 32768;
      int t = v >> 10, k = (v >> 8) & 3, hm = v & 255;
      float base = (k == 0) ? b0[hm] : bh[(k - 1) * 256 + hm];
      const float* lat = latents + t * 256;
      const float* row = HB + (size_t)(k * 256 + hm) * 256;
      float s = base;
      for (int kk = 0; kk < 256; kk += 4)
        s += row[kk] * lat[kk] + row[kk + 1] * lat[kk + 1] +
             row[kk + 2] * lat[kk + 2] + row[kk + 3] * lat[kk + 3];
      beff[v] = s * OMEGA_SC;
    }
    return;
  }

  // ---------------- ka_weff_blob ----------------
  int h = bid & 1, ks = (bid >> 1) & 15, nf = (bid >> 5) & 7, l = bid >> 8;

  {
    int f = tid >> 3, kb = (tid & 7) * 32;
#pragma unroll
    for (int m = 0; m < 32; m += 4) {
      float4 v = *(const float4*)(latents + f * 256 + kb + m);
      lat_t[(kb + m + 0) * 32 + f] = v.x;
      lat_t[(kb + m + 1) * 32 + f] = v.y;
      lat_t[(kb + m + 2) * 32 + f] = v.z;
      lat_t[(kb + m + 3) * 32 + f] = v.w;
    }
  }
  __syncthreads();

  int oo = tid >> 3, jj = tid & 7;
  int o = nf * 32 + oo;
  // permuted fragment position -> original column index i
  int i = (ks >> 1) * 32 + (ks & 1) * 4 + (jj & 3) + 8 * ((jj >> 2) & 1) + 16 * h;
  int r = o * 256 + i;
  const float* rowp = HWh + ((size_t)l * 65536 + (size_t)r) * 256;

  float acc[32];
#pragma unroll
  for (int f = 0; f < 32; ++f) acc[f] = 0.f;

  float curf[16], nxtf[16];
#pragma unroll
  for (int q = 0; q < 4; ++q)
    *(float4*)(curf + q * 4) = *(const float4*)(rowp + q * 4);

  for (int kc = 0; kc < 16; ++kc) {
    if (kc < 15) {
#pragma unroll
      for (int q = 0; q < 4; ++q)
        *(float4*)(nxtf + q * 4) = *(const float4*)(rowp + (kc + 1) * 16 + q * 4);
    }
    const float* lp = lat_t + kc * 512;
#pragma unroll
    for (int m = 0; m < 16; ++m) {
      float hw = curf[m];
#pragma unroll
      for (int fq = 0; fq < 8; ++fq) {
        float4 lv = *(const float4*)(lp + m * 32 + fq * 4);
        acc[fq * 4 + 0] += hw * lv.x;
        acc[fq * 4 + 1] += hw * lv.y;
        acc[fq * 4 + 2] += hw * lv.z;
        acc[fq * 4 + 3] += hw * lv.w;
      }
    }
#pragma unroll
    for (int q = 0; q < 16; ++q) curf[q] = nxtf[q];
  }

  float whv = Wh[l * 65536 + r];
  size_t cbase = (size_t)(nf * 16 + ks) * 1024 + (size_t)h * 256 + (size_t)tid;
#pragma unroll
  for (int t = 0; t < 32; ++t) {
    float w = (acc[t] + whv) * OMEGA_SC;
    _Float16 hi = (_Float16)w;
    _Float16 lo = (_Float16)((w - (float)hi) * LO_SCALE);
    size_t b = (size_t)(t * 3 + l) * 131072 + cbase;
    whblob[b] = hi;
    whblob[b + 512] = lo;
  }
}

// ---------------------------------------------------------------------------
// Kernel B: fused SIREN, software-pipelined over TWO pixel halves.
// Block = one frame x 128 px (halves P0/P1 of 64), 8 waves (512 thr).
// Wave wv owns o-slice [wv*32, wv*32+32) x both 32-px fragments of the
// half being GEMMed; 6 MFMA per ks. While GEMM(P_a, layer l) runs, the SAME
// wave's sine/split VALU for P_b's finished acc interleaves in the MFMA
// shadow (independent regs -> dual-issue; kills the R7 serial MFMA+VALU sum).
// 1 barrier per half-layer (leading store-barrier provably redundant after
// the first). LDS 141KB -> 1 block/CU (2 waves/SIMD).
// Split-fp16 GEMM: D[o][px]=sum_k W[o][k]*x[px][k]; hh->accA, hl+lh->accB,
// out = accA + accB/2048. k-perm contiguous epilogue stores (R10, verified).
// ---------------------------------------------------------------------------
__global__ __launch_bounds__(512, 2) void kb_siren(
    const float* __restrict__ coords, const _Float16* __restrict__ whblob,
    const _Float16* __restrict__ w0blob, const float* __restrict__ beff,
    const float* __restrict__ Wf, const float* __restrict__ bf,
    float* __restrict__ out) {
  __shared__ _Float16 xs_hi[2][64 * 264];
  __shared__ _Float16 xs_lo[2][64 * 264];
  __shared__ float wf_s[768];
  __shared__ float red[1536];  // [kq(4)][px(128)][3]
  int tid = threadIdx.x;
  int bid0 = blockIdx.x;
  int bid = (bid0 & 7) * 128 + (bid0 >> 3);  // XCD swizzle: 4 frames per XCD
  int t = bid >> 5, tile = bid & 31;
  int wv = tid >> 6, lane = tid & 63, col = lane & 31, h = lane >> 5;

  if (tid < 192) {
    // load Wf permuted: wf_s[c*256 + p] = Wf[c*256 + sigma(p)]
    int c = tid >> 6;
    int pq = (tid & 63) * 4;
    int blk = pq >> 5, p32 = pq & 31, hq = p32 >> 4, rr = p32 & 15;
    int src = c * 256 + blk * 32 + 8 * (rr >> 2) + 4 * hq;
    *(float4*)(wf_s + tid * 4) = *(const float4*)(Wf + src);
  }
  if (tid < 128) {
    int half = tid >> 6, row = tid & 63;
    const float* cp = coords + (size_t)(t * 4096 + tile * 128 + tid) * 3;
    float c0 = cp[0], c1 = cp[1], c2 = cp[2];
    H8 hv, lv, z;
#pragma unroll
    for (int j = 0; j < 8; ++j) { hv.h[j] = (_Float16)0.f; lv.h[j] = (_Float16)0.f; z.h[j] = (_Float16)0.f; }
    _Float16 h0 = (_Float16)c0, h1 = (_Float16)c1, h2_ = (_Float16)c2;
    hv.h[0] = h0; hv.h[1] = h1; hv.h[2] = h2_;   // sigma(p)=p for p<4
    lv.h[0] = (_Float16)((c0 - (float)h0) * LO_SCALE);
    lv.h[1] = (_Float16)((c1 - (float)h1) * LO_SCALE);
    lv.h[2] = (_Float16)((c2 - (float)h2_) * LO_SCALE);
    *(f16x8*)(xs_hi[half] + row * 264) = hv.v;
    *(f16x8*)(xs_lo[half] + row * 264) = lv.v;
    *(f16x8*)(xs_hi[half] + row * 264 + 8) = z.v;
    *(f16x8*)(xs_lo[half] + row * 264 + 8) = z.v;
  }
  __syncthreads();

  f32x16 a0A[2], a0B[2], a1A[2], a1B[2];  // [pf] per half

  auto init_bias = [&](int bk, f32x16 (&A)[2], f32x16 (&B)[2]) {
    const float* bp = beff + ((t * 4 + bk) << 8) + wv * 32 + h * 4;
#pragma unroll
    for (int rq = 0; rq < 4; ++rq) {
      float4 bvv = *(const float4*)(bp + rq * 8);
      float ba[4];
      *(float4*)ba = bvv;
#pragma unroll
      for (int q = 0; q < 4; ++q) {
        A[0][rq * 4 + q] = ba[q];
        A[1][rq * 4 + q] = ba[q];
        B[0][rq * 4 + q] = 0.f;
        B[1][rq * 4 + q] = 0.f;
      }
    }
  };

  auto aload2 = [&](const _Float16* blobL, int NS, int ks, f16x8& ah, f16x8& al) {
    const _Float16* p = blobL + (size_t)((wv * NS + ks) * 2) * 512 + lane * 8;
    ah = *(const f16x8*)p;
    al = *(const f16x8*)(p + 512);
  };

  auto bload = [&](int half, int ks, f16x8& b0h, f16x8& b0l, f16x8& b1h, f16x8& b1l) {
    int off0 = col * 264 + ks * 16 + h * 8;
    int off1 = off0 + 32 * 264;
    b0h = *(const f16x8*)(xs_hi[half] + off0);
    b0l = *(const f16x8*)(xs_lo[half] + off0);
    b1h = *(const f16x8*)(xs_hi[half] + off1);
    b1l = *(const f16x8*)(xs_lo[half] + off1);
  };

  auto mfma6 = [&](f16x8 ah, f16x8 al, f16x8 b0h, f16x8 b0l, f16x8 b1h, f16x8 b1l,
                   f32x16 (&A)[2], f32x16 (&B)[2]) {
    A[0] = __builtin_amdgcn_mfma_f32_32x32x16_f16(ah, b0h, A[0], 0, 0, 0);
    A[1] = __builtin_amdgcn_mfma_f32_32x32x16_f16(ah, b1h, A[1], 0, 0, 0);
    B[0] = __builtin_amdgcn_mfma_f32_32x32x16_f16(ah, b0l, B[0], 0, 0, 0);
    B[1] = __builtin_amdgcn_mfma_f32_32x32x16_f16(ah, b1l, B[1], 0, 0, 0);
    B[0] = __builtin_amdgcn_mfma_f32_32x32x16_f16(al, b0h, B[0], 0, 0, 0);
    B[1] = __builtin_amdgcn_mfma_f32_32x32x16_f16(al, b1h, B[1], 0, 0, 0);
  };

  // sin(2*pi*x) via exact HW ops (weights pre-scaled by OMEGA/(2*pi))
  auto sin2pi = [](float x) {
    float f, r;
    asm("v_fract_f32 %0, %1" : "=v"(f) : "v"(x));
    asm("v_sin_f32 %0, %1" : "=v"(r) : "v"(f));
    return r;
  };

  // GEMM of one half's layer, with the OTHER half's activation VALU
  // interleaved into the MFMA shadow (2 sines per ks-step).
  auto gphase = [&](const _Float16* bl, int half,
                    f32x16 (&gA)[2], f32x16 (&gB)[2],
                    f32x16 (&eA)[2], f32x16 (&eB)[2], bool do_epi) {
    f16x8 cah, cal, cb0h, cb0l, cb1h, cb1l;
    f16x8 nah, nal, nb0h, nb0l, nb1h, nb1l;
    aload2(bl, 16, 0, cah, cal);
    bload(half, 0, cb0h, cb0l, cb1h, cb1l);
#pragma unroll
    for (int ks = 0; ks < 16; ++ks) {
      if (ks < 15) {
        aload2(bl, 16, ks + 1, nah, nal);
        bload(half, ks + 1, nb0h, nb0l, nb1h, nb1l);
      }
      mfma6(cah, cal, cb0h, cb0l, cb1h, cb1l, gA, gB);
      if (do_epi) {
        eA[0][ks] = sin2pi(fmaf(eB[0][ks], LO_INV, eA[0][ks]));
        eA[1][ks] = sin2pi(fmaf(eB[1][ks], LO_INV, eA[1][ks]));
      }
      if (ks < 15) {
        cah = nah; cal = nal;
        cb0h = nb0h; cb0l = nb0l; cb1h = nb1h; cb1l = nb1l;
      }
    }
  };

  auto epi_all = [&](f32x16 (&A)[2], f32x16 (&B)[2]) {
#pragma unroll
    for (int pf = 0; pf < 2; ++pf)
#pragma unroll
      for (int r = 0; r < 16; ++r)
        A[pf][r] = sin2pi(fmaf(B[pf][r], LO_INV, A[pf][r]));
  };

  // pack (RTZ hi/lo) + store a half's activated acc into xs[half].
  // lead_bar only needed when no intervening spack since the last reader.
  auto spack = [&](int half, f32x16 (&A)[2], bool lead_bar) {
    if (lead_bar) __syncthreads();
#pragma unroll
    for (int pf = 0; pf < 2; ++pf) {
      HU h0, h1, l0, l1;
#pragma unroll
      for (int q = 0; q < 4; ++q) {
        float va = A[pf][2 * q], vb = A[pf][2 * q + 1];
        h2 hp = __builtin_amdgcn_cvt_pkrtz(va, vb);
        h0.p[q] = hp;
        l0.p[q] = __builtin_amdgcn_cvt_pkrtz((va - (float)hp[0]) * LO_SCALE,
                                             (vb - (float)hp[1]) * LO_SCALE);
        float vc = A[pf][8 + 2 * q], vd = A[pf][8 + 2 * q + 1];
        h2 hq_ = __builtin_amdgcn_cvt_pkrtz(vc, vd);
        h1.p[q] = hq_;
        l1.p[q] = __builtin_amdgcn_cvt_pkrtz((vc - (float)hq_[0]) * LO_SCALE,
                                             (vd - (float)hq_[1]) * LO_SCALE);
      }
      int off = (pf * 32 + col) * 264 + wv * 32 + h * 16;
      *(f16x8*)(xs_hi[half] + off) = h0.v;
      *(f16x8*)(xs_hi[half] + off + 8) = h1.v;
      *(f16x8*)(xs_lo[half] + off) = l0.v;
      *(f16x8*)(xs_lo[half] + off + 8) = l1.v;
    }
    __syncthreads();
  };

  const _Float16* L0 = whblob + (size_t)(t * 3 + 0) * 131072;
  const _Float16* L1 = L0 + 131072;
  const _Float16* L2 = L1 + 131072;
  const _Float16* W0b = w0blob + (size_t)t * 8192;

  // ---- layer 0: both halves (K=16 zero-padded; coords staged in xs)
  init_bias(0, a0A, a0B);
  {
    f16x8 ah, al, b0h, b0l, b1h, b1l;
    aload2(W0b, 1, 0, ah, al);
    bload(0, 0, b0h, b0l, b1h, b1l);
    mfma6(ah, al, b0h, b0l, b1h, b1l, a0A, a0B);
  }
  init_bias(0, a1A, a1B);
  {
    f16x8 ah, al, b0h, b0l, b1h, b1l;
    aload2(W0b, 1, 0, ah, al);
    bload(1, 0, b0h, b0l, b1h, b1l);
    mfma6(ah, al, b0h, b0l, b1h, b1l, a1A, a1B);
  }
  epi_all(a0A, a0B);       // un-overlapped (tiny, once)
  spack(0, a0A, true);     // xs0 <- layer-1 input for P0

  // ---- pipelined hidden layers: G(P_a, l) || E(P_b, l-1/l), then store P_b
  init_bias(1, a0A, a0B);
  gphase(L0, 0, a0A, a0B, a1A, a1B, true);   // E(acc1 @ l0)
  spack(1, a1A, false);
  init_bias(1, a1A, a1B);
  gphase(L0, 1, a1A, a1B, a0A, a0B, true);   // E(acc0 @ l1)
  spack(0, a0A, false);

  init_bias(2, a0A, a0B);
  gphase(L1, 0, a0A, a0B, a1A, a1B, true);
  spack(1, a1A, false);
  init_bias(2, a1A, a1B);
  gphase(L1, 1, a1A, a1B, a0A, a0B, true);
  spack(0, a0A, false);

  init_bias(3, a0A, a0B);
  gphase(L2, 0, a0A, a0B, a1A, a1B, true);
  spack(1, a1A, false);
  init_bias(3, a1A, a1B);
  gphase(L2, 1, a1A, a1B, a0A, a0B, true);
  spack(0, a0A, false);
  epi_all(a1A, a1B);       // tail (un-overlapped, tiny)
  spack(1, a1A, false);

  // ---- final linear (3 outputs), VALU from LDS; 4 k-groups of 64
  {
    float pc0 = 0.f, pc1 = 0.f, pc2 = 0.f;
    int px = tid & 127, kq = tid >> 7;
    int half = px >> 6, row = px & 63;
    const _Float16* xh = xs_hi[half] + row * 264;
    const _Float16* xl = xs_lo[half] + row * 264;
#pragma unroll
    for (int cc = 0; cc < 8; ++cc) {
      int k0 = kq * 64 + cc * 8;
      H8 hv, lv;
      hv.v = *(const f16x8*)(xh + k0);
      lv.v = *(const f16x8*)(xl + k0);
#pragma unroll
      for (int j = 0; j < 8; ++j) {
        float xv = (float)hv.h[j] + (float)lv.h[j] * LO_INV;
        pc0 += xv * wf_s[k0 + j];
        pc1 += xv * wf_s[256 + k0 + j];
        pc2 += xv * wf_s[512 + k0 + j];
      }
    }
    red[kq * 384 + px * 3 + 0] = pc0;
    red[kq * 384 + px * 3 + 1] = pc1;
    red[kq * 384 + px * 3 + 2] = pc2;
    __syncthreads();
    if (tid < 384) {
      int p2 = tid / 3, c = tid - p2 * 3;
      float s = bf[c];
#pragma unroll
      for (int q = 0; q < 4; ++q) s += red[q * 384 + p2 * 3 + c];
      out[(size_t)(t * 4096 + tile * 128 + p2) * 3 + c] = s;
    }
  }
}

// ---------------------------------------------------------------------------
extern "C" void kernel_launch(void* const* d_in, const int* in_sizes, int n_in,
                              void* d_out, int out_size, void* d_ws, size_t ws_size,
                              hipStream_t stream) {
  const float* coords  = (const float*)d_in[0];
  const float* latents = (const float*)d_in[1];
  const float* W0      = (const float*)d_in[2];
  const float* b0      = (const float*)d_in[3];
  const float* Wh      = (const float*)d_in[4];
  const float* bh      = (const float*)d_in[5];
  const float* Wf      = (const float*)d_in[6];
  const float* bf      = (const float*)d_in[7];
  const float* HW0     = (const float*)d_in[8];
  const float* HWh     = (const float*)d_in[9];
  const float* HB      = (const float*)d_in[10];
  float* outp = (float*)d_out;

  char* w = (char*)d_ws;
  _Float16* whblob = (_Float16*)w;                   // 12,582,912 halves
  _Float16* w0blob = (_Float16*)(w + 25165824);      // 262,144 halves
  float*    beff   = (float*)(w + 25690112);         // 32,768 floats

  kab<<<1024, 256, 0, stream>>>(latents, W0, b0, bh, HW0, HB, Wh, HWh,
                                w0blob, beff, whblob);
  kb_siren<<<1024, 512, 0, stream>>>(coords, whblob, w0blob, beff, Wf, bf, outp);
}

// Round 12
// 213.110 us; speedup vs baseline: 1.0854x; 1.0450x over previous
//
#include <hip/hip_runtime.h>
#include <cstdint>
#include <cstddef>

typedef __attribute__((ext_vector_type(8))) _Float16 f16x8;
typedef __attribute__((ext_vector_type(2))) __fp16 h2;
typedef __attribute__((ext_vector_type(16))) float f32x16;

#define LO_SCALE 2048.0f
#define LO_INV   (1.0f / 2048.0f)
// OMEGA/(2*pi): folded into all effective weights/biases so the activation is
// sin(2*pi*acc) = v_fract + v_sin (2 exact HW ops). Wf/bf are NOT scaled.
#define OMEGA_SC 4.774648292756860f

union H8 { f16x8 v; _Float16 h[8]; };
union HU { f16x8 v; h2 p[4]; };

// k-permutation (applied to A-blob, xs stores, Wf load; exact under shared
// perm): storage p (within 32-block: p32 = hq*16 + r) holds original index
// sigma = (r&3) + 8*(r>>2) + 4*hq. Lets the epilogue store C-fragment regs
// 0..15 as 16 CONTIGUOUS halves (2x b128, conflict-free quarter-waves).

// ---------------------------------------------------------------------------
// Fused kernel A+C (unchanged since R10, verified absmax 1.22e-3).
// Blocks [0,768): ka_weff_blob — (OMEGA_SC*Weff) + direct A-fragment blob.
// Blocks [768,1024): kc_small — layer-0 blob + effective biases (both scaled).
// whblob per (tl): [nf(8)][ks(16)][part(2)][lane(64)*8 halves]
// w0blob per t: [nf(8)][part(2)][512 halves]
// beff: [t][k(4)][256] fp32 (scaled), k=0: b0+hb0, k>=1: bh[k-1]+hb[k]
// ---------------------------------------------------------------------------
__global__ __launch_bounds__(256) void kab(
    const float* __restrict__ latents, const float* __restrict__ W0,
    const float* __restrict__ b0, const float* __restrict__ bh,
    const float* __restrict__ HW0, const float* __restrict__ HB,
    const float* __restrict__ Wh, const float* __restrict__ HWh,
    _Float16* __restrict__ w0blob, float* __restrict__ beff,
    _Float16* __restrict__ whblob) {
  __shared__ float lat_t[8192];  // [k][f] : 256 x 32
  int tid = threadIdx.x, bid = blockIdx.x;

  if (bid >= 768) {
    // ---------------- kc_small ----------------
    int id = (bid - 768) * 256 + tid;
    if (id < 32768) {
      int t = id >> 10, rem = id & 1023;
      int r2 = rem & 127, part = r2 >> 6, lane = r2 & 63;
      int nf = rem >> 7;
      int o = nf * 32 + (lane & 31), kc = lane >> 5;
      const float* lat = latents + t * 256;
      H8 outv;
#pragma unroll
      for (int j = 0; j < 8; ++j) outv.h[j] = (_Float16)0.0f;
#pragma unroll
      for (int j = 0; j < 8; ++j) {
        int i = (j & 3) + 8 * (j >> 2) + 16 * kc;  // permuted position -> orig i
        if (i < 3) {
          const float* row = HW0 + (o * 3 + i) * 256;
          float s = W0[o * 3 + i];
          for (int k = 0; k < 256; k += 4)
            s += row[k] * lat[k] + row[k + 1] * lat[k + 1] +
                 row[k + 2] * lat[k + 2] + row[k + 3] * lat[k + 3];
          s *= OMEGA_SC;
          _Float16 hi = (_Float16)s;
          outv.h[j] = part ? (_Float16)((s - (float)hi) * LO_SCALE) : hi;
        }
      }
      *(f16x8*)(w0blob + (size_t)id * 8) = outv.v;
    } else {
      int v = id - 32768;
      int t = v >> 10, k = (v >> 8) & 3, hm = v & 255;
      float base = (k == 0) ? b0[hm] : bh[(k - 1) * 256 + hm];
      const float* lat = latents + t * 256;
      const float* row = HB + (size_t)(k * 256 + hm) * 256;
      float s = base;
      for (int kk = 0; kk < 256; kk += 4)
        s += row[kk] * lat[kk] + row[kk + 1] * lat[kk + 1] +
             row[kk + 2] * lat[kk + 2] + row[kk + 3] * lat[kk + 3];
      beff[v] = s * OMEGA_SC;
    }
    return;
  }

  // ---------------- ka_weff_blob ----------------
  int h = bid & 1, ks = (bid >> 1) & 15, nf = (bid >> 5) & 7, l = bid >> 8;

  {
    int f = tid >> 3, kb = (tid & 7) * 32;
#pragma unroll
    for (int m = 0; m < 32; m += 4) {
      float4 v = *(const float4*)(latents + f * 256 + kb + m);
      lat_t[(kb + m + 0) * 32 + f] = v.x;
      lat_t[(kb + m + 1) * 32 + f] = v.y;
      lat_t[(kb + m + 2) * 32 + f] = v.z;
      lat_t[(kb + m + 3) * 32 + f] = v.w;
    }
  }
  __syncthreads();

  int oo = tid >> 3, jj = tid & 7;
  int o = nf * 32 + oo;
  // permuted fragment position -> original column index i
  int i = (ks >> 1) * 32 + (ks & 1) * 4 + (jj & 3) + 8 * ((jj >> 2) & 1) + 16 * h;
  int r = o * 256 + i;
  const float* rowp = HWh + ((size_t)l * 65536 + (size_t)r) * 256;

  float acc[32];
#pragma unroll
  for (int f = 0; f < 32; ++f) acc[f] = 0.f;

  float curf[16], nxtf[16];
#pragma unroll
  for (int q = 0; q < 4; ++q)
    *(float4*)(curf + q * 4) = *(const float4*)(rowp + q * 4);

  for (int kc = 0; kc < 16; ++kc) {
    if (kc < 15) {
#pragma unroll
      for (int q = 0; q < 4; ++q)
        *(float4*)(nxtf + q * 4) = *(const float4*)(rowp + (kc + 1) * 16 + q * 4);
    }
    const float* lp = lat_t + kc * 512;
#pragma unroll
    for (int m = 0; m < 16; ++m) {
      float hw = curf[m];
#pragma unroll
      for (int fq = 0; fq < 8; ++fq) {
        float4 lv = *(const float4*)(lp + m * 32 + fq * 4);
        acc[fq * 4 + 0] += hw * lv.x;
        acc[fq * 4 + 1] += hw * lv.y;
        acc[fq * 4 + 2] += hw * lv.z;
        acc[fq * 4 + 3] += hw * lv.w;
      }
    }
#pragma unroll
    for (int q = 0; q < 16; ++q) curf[q] = nxtf[q];
  }

  float whv = Wh[l * 65536 + r];
  size_t cbase = (size_t)(nf * 16 + ks) * 1024 + (size_t)h * 256 + (size_t)tid;
#pragma unroll
  for (int t = 0; t < 32; ++t) {
    float w = (acc[t] + whv) * OMEGA_SC;
    _Float16 hi = (_Float16)w;
    _Float16 lo = (_Float16)((w - (float)hi) * LO_SCALE);
    size_t b = (size_t)(t * 3 + l) * 131072 + cbase;
    whblob[b] = hi;
    whblob[b + 512] = lo;
  }
}

// ---------------------------------------------------------------------------
// Kernel B: fused SIREN. Block = one frame x 64 pixels, 4 waves (256 thr).
// Wave wv owns fa=2 o-fragments x fb=2 px-fragments; 12 MFMA per ks.
// R12: depth-3 rotating register pipeline (A in 3 sets, set=(ks+li)%3
// continuous across layers so ks=13..15 slots prefetch NEXT layer's ks=0..2;
// B in 2 sets, reload just-consumed set for ks+2; zero register copies) +
// raw s_barrier with lgkmcnt-only drain (no vmcnt(0) at layer boundaries ->
// cross-layer A loads stay in flight). Attacks the ~50% unattributed stall
// (R3-R11 all pinned at 40-47% MfmaUtil with depth-1 prefetch + draining
// __syncthreads).
// Split-fp16 GEMM: D[o][px]=sum_k W[o][k]*x[px][k]; hh->accA, hl+lh->accB,
// out = accA + accB/2048. k-perm contiguous epilogue stores (R10, verified).
// ---------------------------------------------------------------------------
__global__ __launch_bounds__(256, 2) void kb_siren(
    const float* __restrict__ coords, const _Float16* __restrict__ whblob,
    const _Float16* __restrict__ w0blob, const float* __restrict__ beff,
    const float* __restrict__ Wf, const float* __restrict__ bf,
    float* __restrict__ out) {
  __shared__ _Float16 xs_hi[64 * 264];
  __shared__ _Float16 xs_lo[64 * 264];
  __shared__ float wf_s[768];
  __shared__ float red[768];  // [kq(4)][px(64)][3]
  int tid = threadIdx.x;
  int bid0 = blockIdx.x;
  int bid = (bid0 & 7) * 256 + (bid0 >> 3);  // XCD swizzle: 4 frames per XCD
  int t = bid >> 6, tile = bid & 63;
  int wv = tid >> 6, lane = tid & 63, col = lane & 31, h = lane >> 5;

  if (tid < 192) {
    // load Wf permuted: wf_s[c*256 + p] = Wf[c*256 + sigma(p)]
    int c = tid >> 6;
    int pq = (tid & 63) * 4;
    int blk = pq >> 5, p32 = pq & 31, hq = p32 >> 4, rr = p32 & 15;
    int src = c * 256 + blk * 32 + 8 * (rr >> 2) + 4 * hq;
    *(float4*)(wf_s + tid * 4) = *(const float4*)(Wf + src);
  }
  if (tid < 64) {
    const float* cp = coords + (size_t)(t * 4096 + tile * 64 + tid) * 3;
    float c0 = cp[0], c1 = cp[1], c2 = cp[2];
    H8 hv, lv, z;
#pragma unroll
    for (int j = 0; j < 8; ++j) { hv.h[j] = (_Float16)0.f; lv.h[j] = (_Float16)0.f; z.h[j] = (_Float16)0.f; }
    _Float16 h0 = (_Float16)c0, h1 = (_Float16)c1, h2_ = (_Float16)c2;
    hv.h[0] = h0; hv.h[1] = h1; hv.h[2] = h2_;   // sigma(p)=p for p<4
    lv.h[0] = (_Float16)((c0 - (float)h0) * LO_SCALE);
    lv.h[1] = (_Float16)((c1 - (float)h1) * LO_SCALE);
    lv.h[2] = (_Float16)((c2 - (float)h2_) * LO_SCALE);
    *(f16x8*)(xs_hi + tid * 264) = hv.v;
    *(f16x8*)(xs_lo + tid * 264) = lv.v;
    *(f16x8*)(xs_hi + tid * 264 + 8) = z.v;
    *(f16x8*)(xs_lo + tid * 264 + 8) = z.v;
  }
  __syncthreads();

  // LDS-only barrier: waits ds ops, leaves global loads (vmcnt) in flight.
  auto bar_lds = [] {
    asm volatile("s_waitcnt lgkmcnt(0)" ::: "memory");
    __builtin_amdgcn_s_barrier();
  };

  f32x16 accA[2][2], accB[2][2];  // [fr][pf]

  auto init_bias = [&](int bk) {
#pragma unroll
    for (int fr = 0; fr < 2; ++fr) {
      const float* bp = beff + ((t * 4 + bk) << 8) + (wv * 2 + fr) * 32 + h * 4;
#pragma unroll
      for (int rq = 0; rq < 4; ++rq) {
        float4 bvv = *(const float4*)(bp + rq * 8);
        float ba[4];
        *(float4*)ba = bvv;
#pragma unroll
        for (int q = 0; q < 4; ++q) {
          accA[fr][0][rq * 4 + q] = ba[q];
          accA[fr][1][rq * 4 + q] = ba[q];
          accB[fr][0][rq * 4 + q] = 0.f;
          accB[fr][1][rq * 4 + q] = 0.f;
        }
      }
    }
  };

  struct ASet { f16x8 a0h, a0l, a1h, a1l; };
  struct BSet { f16x8 b0h, b0l, b1h, b1l; };

  auto aload = [&](const _Float16* blobL, int NS, int ks, ASet& s) {
    const _Float16* p0 = blobL + (size_t)(((wv * 2 + 0) * NS + ks) * 2) * 512 + lane * 8;
    const _Float16* p1 = blobL + (size_t)(((wv * 2 + 1) * NS + ks) * 2) * 512 + lane * 8;
    s.a0h = *(const f16x8*)p0;
    s.a0l = *(const f16x8*)(p0 + 512);
    s.a1h = *(const f16x8*)p1;
    s.a1l = *(const f16x8*)(p1 + 512);
  };

  auto bload = [&](int ks, BSet& s) {
    int off0 = col * 264 + ks * 16 + h * 8;
    int off1 = off0 + 32 * 264;
    s.b0h = *(const f16x8*)(xs_hi + off0);
    s.b0l = *(const f16x8*)(xs_lo + off0);
    s.b1h = *(const f16x8*)(xs_hi + off1);
    s.b1l = *(const f16x8*)(xs_lo + off1);
  };

  auto mfma12 = [&](const ASet& a, const BSet& b) {
    __builtin_amdgcn_s_setprio(1);
    accA[0][0] = __builtin_amdgcn_mfma_f32_32x32x16_f16(a.a0h, b.b0h, accA[0][0], 0, 0, 0);
    accA[1][0] = __builtin_amdgcn_mfma_f32_32x32x16_f16(a.a1h, b.b0h, accA[1][0], 0, 0, 0);
    accA[0][1] = __builtin_amdgcn_mfma_f32_32x32x16_f16(a.a0h, b.b1h, accA[0][1], 0, 0, 0);
    accA[1][1] = __builtin_amdgcn_mfma_f32_32x32x16_f16(a.a1h, b.b1h, accA[1][1], 0, 0, 0);
    accB[0][0] = __builtin_amdgcn_mfma_f32_32x32x16_f16(a.a0h, b.b0l, accB[0][0], 0, 0, 0);
    accB[1][0] = __builtin_amdgcn_mfma_f32_32x32x16_f16(a.a1h, b.b0l, accB[1][0], 0, 0, 0);
    accB[0][1] = __builtin_amdgcn_mfma_f32_32x32x16_f16(a.a0h, b.b1l, accB[0][1], 0, 0, 0);
    accB[1][1] = __builtin_amdgcn_mfma_f32_32x32x16_f16(a.a1h, b.b1l, accB[1][1], 0, 0, 0);
    accB[0][0] = __builtin_amdgcn_mfma_f32_32x32x16_f16(a.a0l, b.b0h, accB[0][0], 0, 0, 0);
    accB[1][0] = __builtin_amdgcn_mfma_f32_32x32x16_f16(a.a1l, b.b0h, accB[1][0], 0, 0, 0);
    accB[0][1] = __builtin_amdgcn_mfma_f32_32x32x16_f16(a.a0l, b.b1h, accB[0][1], 0, 0, 0);
    accB[1][1] = __builtin_amdgcn_mfma_f32_32x32x16_f16(a.a1l, b.b1h, accB[1][1], 0, 0, 0);
    __builtin_amdgcn_s_setprio(0);
  };

  // sin(2*pi*x) via exact HW ops (weights pre-scaled by OMEGA/(2*pi))
  auto sin2pi = [](float x) {
    float f, r;
    asm("v_fract_f32 %0, %1" : "=v"(f) : "v"(x));
    asm("v_sin_f32 %0, %1" : "=v"(r) : "v"(f));
    return r;
  };

  // activation + packed RTZ split + k-perm CONTIGUOUS stores, with raw
  // LDS-only barriers (global prefetch loads stay in flight across them).
  auto epilogue = [&]() {
#pragma unroll
    for (int fr = 0; fr < 2; ++fr)
#pragma unroll
      for (int pf = 0; pf < 2; ++pf)
#pragma unroll
        for (int r = 0; r < 16; ++r)
          accA[fr][pf][r] = sin2pi(fmaf(accB[fr][pf][r], LO_INV, accA[fr][pf][r]));
    bar_lds();  // all waves done reading xs for this layer
#pragma unroll
    for (int fr = 0; fr < 2; ++fr)
#pragma unroll
      for (int pf = 0; pf < 2; ++pf) {
        HU h0, h1, l0, l1;
#pragma unroll
        for (int q = 0; q < 4; ++q) {
          float va = accA[fr][pf][2 * q], vb = accA[fr][pf][2 * q + 1];
          h2 hp = __builtin_amdgcn_cvt_pkrtz(va, vb);
          h0.p[q] = hp;
          l0.p[q] = __builtin_amdgcn_cvt_pkrtz((va - (float)hp[0]) * LO_SCALE,
                                               (vb - (float)hp[1]) * LO_SCALE);
          float vc = accA[fr][pf][8 + 2 * q], vd = accA[fr][pf][8 + 2 * q + 1];
          h2 hq_ = __builtin_amdgcn_cvt_pkrtz(vc, vd);
          h1.p[q] = hq_;
          l1.p[q] = __builtin_amdgcn_cvt_pkrtz((vc - (float)hq_[0]) * LO_SCALE,
                                               (vd - (float)hq_[1]) * LO_SCALE);
        }
        int off = (pf * 32 + col) * 264 + wv * 64 + fr * 32 + h * 16;
        *(f16x8*)(xs_hi + off) = h0.v;
        *(f16x8*)(xs_hi + off + 8) = h1.v;
        *(f16x8*)(xs_lo + off) = l0.v;
        *(f16x8*)(xs_lo + off + 8) = l1.v;
      }
    bar_lds();  // stores visible before next layer's B reads
  };

  const _Float16* L0 = whblob + (size_t)(t * 3) * 131072;
  ASet A[3];
  BSet Bv[2];

  // ---- layer 0 (K=16 zero-padded; coords staged in xs[.., 0..15])
  init_bias(0);
  aload(w0blob + (size_t)t * 8192, 1, 0, A[0]);
  bload(0, Bv[0]);
  mfma12(A[0], Bv[0]);
  // prefetch hidden L0 ks=0..2 (depth-3 pipeline bootstrap) under epilogue
  aload(L0, 16, 0, A[0]);
  aload(L0, 16, 1, A[1]);
  aload(L0, 16, 2, A[2]);
  epilogue();

  // ---- hidden layers: rotating sets, zero copies, cross-layer prefetch.
  // Set index (ks + li) % 3 is continuous across layers (16 = 1 mod 3).
#pragma unroll
  for (int li = 0; li < 3; ++li) {
    init_bias(li + 1);
    const _Float16* bl = whblob + (size_t)(t * 3 + li) * 131072;
    const _Float16* bln = whblob + (size_t)(t * 3 + li + 1) * 131072;
    bload(0, Bv[0]);
    bload(1, Bv[1]);
#pragma unroll
    for (int ks = 0; ks < 16; ++ks) {
      mfma12(A[(ks + li) % 3], Bv[ks & 1]);
      if (ks + 3 < 16) {
        aload(bl, 16, ks + 3, A[(ks + li) % 3]);       // refill consumed set
      } else if (li < 2) {
        aload(bln, 16, ks - 13, A[(ks + li) % 3]);     // next layer ks 0..2
      }
      if (ks + 2 < 16) bload(ks + 2, Bv[ks & 1]);
    }
    epilogue();
  }

  // ---- final linear (3 outputs), VALU from LDS; 4 k-groups of 64
  {
    float pc0 = 0.f, pc1 = 0.f, pc2 = 0.f;
    int px = tid & 63, kq = tid >> 6;
#pragma unroll
    for (int cc = 0; cc < 8; ++cc) {
      int k0 = kq * 64 + cc * 8;
      H8 hv, lv;
      hv.v = *(const f16x8*)(xs_hi + px * 264 + k0);
      lv.v = *(const f16x8*)(xs_lo + px * 264 + k0);
#pragma unroll
      for (int j = 0; j < 8; ++j) {
        float xv = (float)hv.h[j] + (float)lv.h[j] * LO_INV;
        pc0 += xv * wf_s[k0 + j];
        pc1 += xv * wf_s[256 + k0 + j];
        pc2 += xv * wf_s[512 + k0 + j];
      }
    }
    red[kq * 192 + px * 3 + 0] = pc0;
    red[kq * 192 + px * 3 + 1] = pc1;
    red[kq * 192 + px * 3 + 2] = pc2;
    __syncthreads();
    if (tid < 192) {
      int p2 = tid / 3, c = tid - p2 * 3;
      float s = bf[c];
#pragma unroll
      for (int q = 0; q < 4; ++q) s += red[q * 192 + p2 * 3 + c];
      out[(size_t)(t * 4096 + tile * 64 + p2) * 3 + c] = s;
    }
  }
}

// ---------------------------------------------------------------------------
extern "C" void kernel_launch(void* const* d_in, const int* in_sizes, int n_in,
                              void* d_out, int out_size, void* d_ws, size_t ws_size,
                              hipStream_t stream) {
  const float* coords  = (const float*)d_in[0];
  const float* latents = (const float*)d_in[1];
  const float* W0      = (const float*)d_in[2];
  const float* b0      = (const float*)d_in[3];
  const float* Wh      = (const float*)d_in[4];
  const float* bh      = (const float*)d_in[5];
  const float* Wf      = (const float*)d_in[6];
  const float* bf      = (const float*)d_in[7];
  const float* HW0     = (const float*)d_in[8];
  const float* HWh     = (const float*)d_in[9];
  const float* HB      = (const float*)d_in[10];
  float* outp = (float*)d_out;

  char* w = (char*)d_ws;
  _Float16* whblob = (_Float16*)w;                   // 12,582,912 halves
  _Float16* w0blob = (_Float16*)(w + 25165824);      // 262,144 halves
  float*    beff   = (float*)(w + 25690112);         // 32,768 floats

  kab<<<1024, 256, 0, stream>>>(latents, W0, b0, bh, HW0, HB, Wh, HWh,
                                w0blob, beff, whblob);
  kb_siren<<<2048, 256, 0, stream>>>(coords, whblob, w0blob, beff, Wf, bf, outp);
}